// Round 3
// baseline (100.122 us; speedup 1.0000x reference)
//
#include <hip/hip_runtime.h>
#include <hip/hip_bf16.h>
#include <math.h>

#define NLOOP 8
#define BB 8
#define LLEN 2048
#define DD 768
#define VV 50288
#define HALT 50277
#define EPSF 1e-5f

#define BN 64
#define BKK 32
#define KSTEPS (DD / BKK)              // 24
#define NBLK ((VV + BN - 1) / BN)      // 786

typedef short bf16x8 __attribute__((ext_vector_type(8)));
typedef float f32x4 __attribute__((ext_vector_type(4)));

__device__ __forceinline__ unsigned short f32_to_bf16(float f) {
    unsigned u = __builtin_bit_cast(unsigned, f);
    unsigned r = (u + 0x7FFFu + ((u >> 16) & 1u)) >> 16;
    return (unsigned short)r;
}

// ---------------- Kernel 1: gather + RMSNorm + target logits ----------------
__global__ __launch_bounds__(256) void k_prep(
    const float* __restrict__ x, const float* __restrict__ res,
    const float* __restrict__ nw, const float* __restrict__ W,
    const int* __restrict__ ans_starts, const int* __restrict__ chain_targets,
    const int* __restrict__ chain_lens,
    unsigned short* __restrict__ hbf, float* __restrict__ tgt_logit,
    unsigned int* __restrict__ counter)
{
    if (blockIdx.x == 0 && threadIdx.x == 0) *counter = 0u;   // for k_combine

    int lb = blockIdx.x, l = lb >> 3, b = lb & 7;
    int tid = threadIdx.x, lane = tid & 63, wave = tid >> 6;
    int as = ans_starts[b];
    int pos = as - 1;
    pos = pos < 0 ? 0 : (pos > LLEN - 1 ? LLEN - 1 : pos);
    size_t base = ((size_t)lb * LLEN + (size_t)pos) * DD;

    float hv[3];
    float ss = 0.f;
#pragma unroll
    for (int i = 0; i < 3; ++i) {
        int d = tid + i * 256;
        float v = x[base + d] + res[base + d];
        hv[i] = v;
        ss += v * v;
    }
#pragma unroll
    for (int off = 32; off; off >>= 1) ss += __shfl_down(ss, off);
    __shared__ float red[4];
    __shared__ float bc;
    if (lane == 0) red[wave] = ss;
    __syncthreads();
    if (tid == 0) bc = red[0] + red[1] + red[2] + red[3];
    __syncthreads();
    float rs = rsqrtf(bc / (float)DD + EPSF);

    int cl = chain_lens[b];
    int tix = l < cl - 1 ? l : cl - 1;
    int tgt = chain_targets[b * NLOOP + tix];
    bool tok = (tgt >= 0) && (tgt < VV);

    float dp = 0.f;
#pragma unroll
    for (int i = 0; i < 3; ++i) {
        int d = tid + i * 256;
        float h = hv[i] * rs * nw[d];
        hbf[(size_t)lb * DD + d] = f32_to_bf16(h);
        if (tok) dp += h * W[(size_t)tgt * DD + d];
    }
#pragma unroll
    for (int off = 32; off; off >>= 1) dp += __shfl_down(dp, off);
    __syncthreads();
    if (lane == 0) red[wave] = dp;
    __syncthreads();
    if (tid == 0) tgt_logit[lb] = red[0] + red[1] + red[2] + red[3];
}

// ---------------- Kernel 2: barrier-free direct-fragment MFMA logits --------
// A (h, bf16, L2-resident) and B (W rows, f32->bf16 in regs) both loaded
// straight into MFMA fragment layout. No data LDS, no main-loop barriers.
// Partials written TRANSPOSED: pmax[row * NBLK + blk] for coalesced combine.
__global__ __launch_bounds__(256) void k_logits(
    const float* __restrict__ W, const unsigned short* __restrict__ hbf,
    float* __restrict__ pmax, float* __restrict__ psum, int* __restrict__ parg)
{
    int blk = blockIdx.x;
    int v0 = blk * BN;
    int tid = threadIdx.x;
    int wave = tid >> 6, lane = tid & 63, q = lane >> 4, c = lane & 15;

    int brow = v0 + wave * 16 + c;
    int browc = brow < VV ? brow : 0;          // clamp; garbage cols masked later
    const float* Bp = W + (size_t)browc * DD + q * 8;
    const unsigned short* Ap = hbf + (size_t)c * DD + q * 8;

    f32x4 acc[4];
#pragma unroll
    for (int m = 0; m < 4; ++m) acc[m] = (f32x4){0.f, 0.f, 0.f, 0.f};

    // two in-flight tile register sets (static indexing only)
    bf16x8 a0_[4]; float4 b0_[2];
    bf16x8 a1_[4]; float4 b1_[2];

    auto load0 = [&](int ks) {
        int ko = ks * BKK;
#pragma unroll
        for (int m = 0; m < 4; ++m)
            a0_[m] = *(const bf16x8*)(Ap + (size_t)m * 16 * DD + ko);
        b0_[0] = *(const float4*)(Bp + ko);
        b0_[1] = *(const float4*)(Bp + ko + 4);
    };
    auto load1 = [&](int ks) {
        int ko = ks * BKK;
#pragma unroll
        for (int m = 0; m < 4; ++m)
            a1_[m] = *(const bf16x8*)(Ap + (size_t)m * 16 * DD + ko);
        b1_[0] = *(const float4*)(Bp + ko);
        b1_[1] = *(const float4*)(Bp + ko + 4);
    };
    auto step = [&](bf16x8* a, float4* b) {
        bf16x8 bf;
        bf[0] = (short)f32_to_bf16(b[0].x);
        bf[1] = (short)f32_to_bf16(b[0].y);
        bf[2] = (short)f32_to_bf16(b[0].z);
        bf[3] = (short)f32_to_bf16(b[0].w);
        bf[4] = (short)f32_to_bf16(b[1].x);
        bf[5] = (short)f32_to_bf16(b[1].y);
        bf[6] = (short)f32_to_bf16(b[1].z);
        bf[7] = (short)f32_to_bf16(b[1].w);
        acc[0] = __builtin_amdgcn_mfma_f32_16x16x32_bf16(a[0], bf, acc[0], 0, 0, 0);
        acc[1] = __builtin_amdgcn_mfma_f32_16x16x32_bf16(a[1], bf, acc[1], 0, 0, 0);
        acc[2] = __builtin_amdgcn_mfma_f32_16x16x32_bf16(a[2], bf, acc[2], 0, 0, 0);
        acc[3] = __builtin_amdgcn_mfma_f32_16x16x32_bf16(a[3], bf, acc[3], 0, 0, 0);
    };

    load0(0);
    load1(1);
#pragma unroll
    for (int ks = 0; ks < KSTEPS; ks += 2) {
        step(a0_, b0_);
        if (ks + 2 < KSTEPS) load0(ks + 2);
        step(a1_, b1_);
        if (ks + 3 < KSTEPS) load1(ks + 3);
    }

    // ---- fused block-level max / argmax / sumexp over this block's 64 cols ----
    __shared__ float wmaxs[4][64];
    __shared__ float wsums[4][64];
    __shared__ int   wargs[4][64];
    __shared__ float bmaxs[64];
    __shared__ int   bargs[64];

    int colg = v0 + wave * 16 + c;
    bool cval = colg < VV;
    const float NEGINF = -__builtin_inff();

#pragma unroll
    for (int m = 0; m < 4; ++m) {
#pragma unroll
        for (int r = 0; r < 4; ++r) {
            float val = cval ? acc[m][r] : NEGINF;
            int idx = colg;
#pragma unroll
            for (int off = 1; off < 16; off <<= 1) {
                float ov = __shfl_xor(val, off);
                int oi = __shfl_xor(idx, off);
                if (ov > val || (ov == val && oi < idx)) { val = ov; idx = oi; }
            }
            if (c == 0) {
                int row = 16 * m + 4 * q + r;
                wmaxs[wave][row] = val;
                wargs[wave][row] = idx;
            }
        }
    }
    __syncthreads();
    if (tid < 64) {
        float M = NEGINF; int A_ = 0x7fffffff;
#pragma unroll
        for (int w = 0; w < 4; ++w) {
            float v = wmaxs[w][tid];
            if (v > M) { M = v; A_ = wargs[w][tid]; }
        }
        bmaxs[tid] = M; bargs[tid] = A_;
    }
    __syncthreads();
#pragma unroll
    for (int m = 0; m < 4; ++m) {
#pragma unroll
        for (int r = 0; r < 4; ++r) {
            int row = 16 * m + 4 * q + r;
            float M = bmaxs[row];
            float e = cval ? __expf(acc[m][r] - M) : 0.f;
#pragma unroll
            for (int off = 1; off < 16; off <<= 1) e += __shfl_xor(e, off);
            if (c == 0) wsums[wave][row] = e;
        }
    }
    __syncthreads();
    if (tid < 64) {
        float s = wsums[0][tid] + wsums[1][tid] + wsums[2][tid] + wsums[3][tid];
        pmax[(size_t)tid * NBLK + blk] = bmaxs[tid];
        psum[(size_t)tid * NBLK + blk] = s;
        parg[(size_t)tid * NBLK + blk] = bargs[tid];
    }
}

// ------- Kernel 3: parallel combine + fused last-block scalar epilogue ------
__global__ __launch_bounds__(256) void k_combine(
    const float* __restrict__ pmax, const float* __restrict__ psum,
    const int* __restrict__ parg, const float* __restrict__ tgt_logit,
    const int* __restrict__ ans_starts, const int* __restrict__ chain_targets,
    const int* __restrict__ chain_lens,
    float* __restrict__ logZ, int* __restrict__ pred,
    unsigned int* __restrict__ counter, float* __restrict__ out)
{
    int r = blockIdx.x;                 // row 0..63
    int tid = threadIdx.x;
    int wave = tid >> 6, lane = tid & 63;
    const float NEGINF = -__builtin_inff();

    const float* pm = pmax + (size_t)r * NBLK;
    const float* ps = psum + (size_t)r * NBLK;
    const int*   pa = parg + (size_t)r * NBLK;

    float M = NEGINF; int A_ = 0x7fffffff;
    for (int i = tid; i < NBLK; i += 256) {
        float m = pm[i];
        int a = pa[i];
        if (m > M || (m == M && a < A_)) { M = m; A_ = a; }
    }
#pragma unroll
    for (int off = 1; off < 64; off <<= 1) {
        float ov = __shfl_xor(M, off);
        int oa = __shfl_xor(A_, off);
        if (ov > M || (ov == M && oa < A_)) { M = ov; A_ = oa; }
    }
    __shared__ float sm[4]; __shared__ int sa[4]; __shared__ float ssum[4];
    __shared__ int lastflag;
    if (lane == 0) { sm[wave] = M; sa[wave] = A_; }
    __syncthreads();
    if (tid == 0) {
#pragma unroll
        for (int w = 1; w < 4; ++w)
            if (sm[w] > sm[0] || (sm[w] == sm[0] && sa[w] < sa[0])) { sm[0] = sm[w]; sa[0] = sa[w]; }
    }
    __syncthreads();
    float Mg = sm[0];

    float S = 0.f;
    for (int i = tid; i < NBLK; i += 256)
        S += ps[i] * __expf(pm[i] - Mg);
#pragma unroll
    for (int off = 1; off < 64; off <<= 1) S += __shfl_xor(S, off);
    if (lane == 0) ssum[wave] = S;
    __syncthreads();
    if (tid == 0) {
        float lz = Mg + logf(ssum[0] + ssum[1] + ssum[2] + ssum[3]);
        __hip_atomic_store(&logZ[r], lz, __ATOMIC_RELAXED, __HIP_MEMORY_SCOPE_AGENT);
        __hip_atomic_store(&pred[r], sa[0], __ATOMIC_RELAXED, __HIP_MEMORY_SCOPE_AGENT);
        __threadfence();                               // release
        unsigned int old = atomicAdd(counter, 1u);     // device-scope RMW
        lastflag = (old == 63u) ? 1 : 0;
    }
    __syncthreads();
    if (lastflag == 0) return;

    // ---- last block: scalar epilogue ----
    __threadfence();                                   // acquire
    __shared__ float lzs[64]; __shared__ int prs[64];
    if (tid < 64) {
        lzs[tid] = __hip_atomic_load(&logZ[tid], __ATOMIC_RELAXED, __HIP_MEMORY_SCOPE_AGENT);
        prs[tid] = __hip_atomic_load(&pred[tid], __ATOMIC_RELAXED, __HIP_MEMORY_SCOPE_AGENT);
    }
    __syncthreads();
    if (tid == 0) {
        float loop_loss[NLOOP], loop_acc[NLOOP], hasf[NLOOP];
        float n_has = 0.f, hms = 0.f, hcs = 0.f;
        for (int l = 0; l < NLOOP; ++l) {
            float cnt = 0.f, se = 0.f, sc = 0.f;
            for (int b = 0; b < BB; ++b) {
                int cl = chain_lens[b];
                int ti = l < cl - 1 ? l : cl - 1;
                int tgt = chain_targets[b * NLOOP + ti];
                int as = ans_starts[b];
                bool valid = (as >= 1) && (as < LLEN) && (tgt < VV);
                int idx = l * BB + b;
                float ce = lzs[idx] - tgt_logit[idx];
                float corr = (prs[idx] == tgt) ? 1.f : 0.f;
                if (valid) {
                    cnt += 1.f; se += ce; sc += corr;
                    if (tgt == HALT) { hms += 1.f; hcs += corr; }
                }
            }
            bool has = cnt > 0.f;
            hasf[l] = has ? 1.f : 0.f;
            n_has += hasf[l];
            float denom = cnt > 1.f ? cnt : 1.f;
            loop_loss[l] = has ? se / denom : 0.f;
            loop_acc[l]  = has ? sc / denom : 0.f;
        }
        float nn = n_has > 1.f ? n_has : 1.f;
        float avg_loss = 0.f, avg_acc = 0.f;
        for (int l = 0; l < NLOOP; ++l) {
            avg_loss += loop_loss[l] * hasf[l];
            avg_acc  += loop_acc[l]  * hasf[l];
        }
        avg_loss /= nn; avg_acc /= nn;
        int last_valid = NLOOP - 1;   // matches jnp.argmax on all-false reversed
        for (int l = NLOOP - 1; l >= 0; --l) if (hasf[l] > 0.f) { last_valid = l; break; }
        float ams = 0.f, aacc = 0.f;
        for (int l = 0; l < NLOOP; ++l) {
            float mask = (n_has > 1.f) ? (hasf[l] * ((l != last_valid) ? 1.f : 0.f)) : hasf[l];
            ams += mask; aacc += loop_acc[l] * mask;
        }
        float answer_acc = (ams > 0.f) ? (aacc / (ams > 1.f ? ams : 1.f)) : avg_acc;
        float halt_acc = (hms > 0.f) ? (hcs / (hms > 1.f ? hms : 1.f)) : 0.f;
        out[0] = avg_loss; out[1] = avg_acc; out[2] = answer_acc; out[3] = halt_acc;
    }
}

extern "C" void kernel_launch(void* const* d_in, const int* in_sizes, int n_in,
                              void* d_out, int out_size, void* d_ws, size_t ws_size,
                              hipStream_t stream) {
    const float* x   = (const float*)d_in[0];
    const float* res = (const float*)d_in[1];
    const float* nw  = (const float*)d_in[2];
    const float* W   = (const float*)d_in[3];
    const int* ans   = (const int*)d_in[4];
    const int* ct    = (const int*)d_in[5];
    const int* cl    = (const int*)d_in[6];
    float* out = (float*)d_out;

    char* ws = (char*)d_ws;
    unsigned short* hbf = (unsigned short*)ws;                       // 96 KiB
    float* tgtl = (float*)(ws + 98304);                              // 256 B
    size_t off = 98560;
    float* pmax = (float*)(ws + off);  off += (size_t)64 * NBLK * 4;
    float* psum = (float*)(ws + off);  off += (size_t)64 * NBLK * 4;
    int*   parg = (int*)  (ws + off);  off += (size_t)64 * NBLK * 4;
    float* logZ = (float*)(ws + off);  off += 256;
    int*   pred = (int*)  (ws + off);  off += 256;
    unsigned int* counter = (unsigned int*)(ws + off); off += 256;

    k_prep<<<64, 256, 0, stream>>>(x, res, nw, W, ans, ct, cl, hbf, tgtl, counter);
    k_logits<<<NBLK, 256, 0, stream>>>(W, hbf, pmax, psum, parg);
    k_combine<<<64, 256, 0, stream>>>(pmax, psum, parg, tgtl, ans, ct, cl,
                                      logZ, pred, counter, out);
}

// Round 4
// 64.237 us; speedup vs baseline: 1.5586x; 1.5586x over previous
//
#include <hip/hip_runtime.h>
#include <hip/hip_bf16.h>
#include <math.h>

#define NLOOP 8
#define BB 8
#define LLEN 2048
#define DD 768
#define VV 50288
#define HALT 50277
#define EPSF 1e-5f

#define BN 64
#define BKK 32
#define KSTEPS (DD / BKK)              // 24
#define NBLK ((VV + BN - 1) / BN)      // 786

typedef short bf16x8 __attribute__((ext_vector_type(8)));
typedef float f32x4 __attribute__((ext_vector_type(4)));

__device__ __forceinline__ unsigned short f32_to_bf16(float f) {
    unsigned u = __builtin_bit_cast(unsigned, f);
    unsigned r = (u + 0x7FFFu + ((u >> 16) & 1u)) >> 16;
    return (unsigned short)r;
}

// ---------------- Kernel 1: gather + RMSNorm + target logits ----------------
__global__ __launch_bounds__(256) void k_prep(
    const float* __restrict__ x, const float* __restrict__ res,
    const float* __restrict__ nw, const float* __restrict__ W,
    const int* __restrict__ ans_starts, const int* __restrict__ chain_targets,
    const int* __restrict__ chain_lens,
    unsigned short* __restrict__ hbf, float* __restrict__ tgt_logit,
    unsigned int* __restrict__ counter)
{
    if (blockIdx.x == 0 && threadIdx.x == 0) *counter = 0u;   // for k_combine

    int lb = blockIdx.x, l = lb >> 3, b = lb & 7;
    int tid = threadIdx.x, lane = tid & 63, wave = tid >> 6;
    int as = ans_starts[b];
    int pos = as - 1;
    pos = pos < 0 ? 0 : (pos > LLEN - 1 ? LLEN - 1 : pos);
    size_t base = ((size_t)lb * LLEN + (size_t)pos) * DD;

    float hv[3];
    float ss = 0.f;
#pragma unroll
    for (int i = 0; i < 3; ++i) {
        int d = tid + i * 256;
        float v = x[base + d] + res[base + d];
        hv[i] = v;
        ss += v * v;
    }
#pragma unroll
    for (int off = 32; off; off >>= 1) ss += __shfl_down(ss, off);
    __shared__ float red[4];
    __shared__ float bc;
    if (lane == 0) red[wave] = ss;
    __syncthreads();
    if (tid == 0) bc = red[0] + red[1] + red[2] + red[3];
    __syncthreads();
    float rs = rsqrtf(bc / (float)DD + EPSF);

    int cl = chain_lens[b];
    int tix = l < cl - 1 ? l : cl - 1;
    int tgt = chain_targets[b * NLOOP + tix];
    bool tok = (tgt >= 0) && (tgt < VV);

    float dp = 0.f;
#pragma unroll
    for (int i = 0; i < 3; ++i) {
        int d = tid + i * 256;
        float h = hv[i] * rs * nw[d];
        hbf[(size_t)lb * DD + d] = f32_to_bf16(h);
        if (tok) dp += h * W[(size_t)tgt * DD + d];
    }
#pragma unroll
    for (int off = 32; off; off >>= 1) dp += __shfl_down(dp, off);
    __syncthreads();
    if (lane == 0) red[wave] = dp;
    __syncthreads();
    if (tid == 0) tgt_logit[lb] = red[0] + red[1] + red[2] + red[3];
}

// ---------------- Kernel 2: A-in-registers MFMA logits ----------------------
// Wave w owns m-tile w (h rows 16w..16w+15) x all 64 block cols.
// A (h) preloaded to 24 bf16x8 regs once; B (W) staged global->reg->LDS,
// double-buffered, 2-deep register prefetch, 1 barrier per K-step.
// Row reduction is wave-internal (16-lane butterfly) -- no LDS, no barriers.
// Partials written TRANSPOSED: pmax[row * NBLK + blk].
__global__ __launch_bounds__(256) void k_logits(
    const float* __restrict__ W, const unsigned short* __restrict__ hbf,
    float* __restrict__ pmax, float* __restrict__ psum, int* __restrict__ parg)
{
    __shared__ unsigned short Bs[2][64 * 56];   // 112B row stride (16B aligned, 2-way banks)

    int blk = blockIdx.x;
    int v0 = blk * BN;
    int tid = threadIdx.x;
    int wave = tid >> 6, lane = tid & 63, q = lane >> 4, c = lane & 15;

    // ---- A preload: h row (16*wave + c), k = ks*32 + q*8 + j ----
    const unsigned short* Ap = hbf + (size_t)(16 * wave + c) * DD + q * 8;
    bf16x8 A[KSTEPS];
#pragma unroll
    for (int ks = 0; ks < KSTEPS; ++ks)
        A[ks] = *(const bf16x8*)(Ap + ks * BKK);

    // ---- B staging: thread loads rows r1, r1+32; 4 consecutive f32 at koff ----
    int r1 = tid >> 3, koff = (tid & 7) * 4;
    int vB0 = v0 + r1, vB1 = v0 + r1 + 32;
    const float* gB0 = W + (size_t)(vB0 < VV ? vB0 : 0) * DD + koff;  // clamp; cols masked later
    const float* gB1 = W + (size_t)(vB1 < VV ? vB1 : 0) * DD + koff;

    f32x4 acc[4];
#pragma unroll
    for (int n = 0; n < 4; ++n) acc[n] = (f32x4){0.f, 0.f, 0.f, 0.f};

    auto stage_write = [&](int bufi, const float4& ra, const float4& rb) {
        ushort4 w0, w1;
        w0.x = f32_to_bf16(ra.x); w0.y = f32_to_bf16(ra.y);
        w0.z = f32_to_bf16(ra.z); w0.w = f32_to_bf16(ra.w);
        w1.x = f32_to_bf16(rb.x); w1.y = f32_to_bf16(rb.y);
        w1.z = f32_to_bf16(rb.z); w1.w = f32_to_bf16(rb.w);
        *(ushort4*)&Bs[bufi][r1 * 56 + koff] = w0;
        *(ushort4*)&Bs[bufi][(r1 + 32) * 56 + koff] = w1;
    };
    auto mfma_step = [&](int bufi, int ks) {
        bf16x8 f0 = *(const bf16x8*)&Bs[bufi][(c +  0) * 56 + q * 8];
        bf16x8 f1 = *(const bf16x8*)&Bs[bufi][(c + 16) * 56 + q * 8];
        bf16x8 f2 = *(const bf16x8*)&Bs[bufi][(c + 32) * 56 + q * 8];
        bf16x8 f3 = *(const bf16x8*)&Bs[bufi][(c + 48) * 56 + q * 8];
        acc[0] = __builtin_amdgcn_mfma_f32_16x16x32_bf16(A[ks], f0, acc[0], 0, 0, 0);
        acc[1] = __builtin_amdgcn_mfma_f32_16x16x32_bf16(A[ks], f1, acc[1], 0, 0, 0);
        acc[2] = __builtin_amdgcn_mfma_f32_16x16x32_bf16(A[ks], f2, acc[2], 0, 0, 0);
        acc[3] = __builtin_amdgcn_mfma_f32_16x16x32_bf16(A[ks], f3, acc[3], 0, 0, 0);
    };

    // 2-deep register pipeline (named sets, static indexing)
    float4 s0a = *(const float4*)(gB0 + 0);
    float4 s0b = *(const float4*)(gB1 + 0);
    float4 s1a = *(const float4*)(gB0 + BKK);
    float4 s1b = *(const float4*)(gB1 + BKK);

#pragma unroll
    for (int kp = 0; kp < KSTEPS / 2; ++kp) {
        // even step ks = 2kp -> Bs[0]
        stage_write(0, s0a, s0b);
        __syncthreads();
        if (kp < KSTEPS / 2 - 1) {
            s0a = *(const float4*)(gB0 + (2 * kp + 2) * BKK);
            s0b = *(const float4*)(gB1 + (2 * kp + 2) * BKK);
        }
        mfma_step(0, 2 * kp);
        // odd step ks = 2kp+1 -> Bs[1]
        stage_write(1, s1a, s1b);
        __syncthreads();
        if (kp < KSTEPS / 2 - 1) {
            s1a = *(const float4*)(gB0 + (2 * kp + 3) * BKK);
            s1b = *(const float4*)(gB1 + (2 * kp + 3) * BKK);
        }
        mfma_step(1, 2 * kp + 1);
    }

    // ---- wave-internal per-row max / argmax / sumexp over 64 block cols ----
    const float NEGINF = -__builtin_inff();
#pragma unroll
    for (int r = 0; r < 4; ++r) {
        float val = NEGINF; int idx = 0x7fffffff;
#pragma unroll
        for (int n = 0; n < 4; ++n) {
            int colg = v0 + 16 * n + c;
            float v = (colg < VV) ? acc[n][r] : NEGINF;
            if (v > val || (v == val && colg < idx)) { val = v; idx = colg; }
        }
#pragma unroll
        for (int off = 1; off < 16; off <<= 1) {
            float ov = __shfl_xor(val, off);
            int oi = __shfl_xor(idx, off);
            if (ov > val || (ov == val && oi < idx)) { val = ov; idx = oi; }
        }
        float M = val;          // all 16 lanes of the q-group hold the row max
        float e = 0.f;
#pragma unroll
        for (int n = 0; n < 4; ++n) {
            int colg = v0 + 16 * n + c;
            e += (colg < VV) ? __expf(acc[n][r] - M) : 0.f;
        }
#pragma unroll
        for (int off = 1; off < 16; off <<= 1) e += __shfl_xor(e, off);
        if (c == 0) {
            int row = 16 * wave + 4 * q + r;
            pmax[(size_t)row * NBLK + blk] = M;
            psum[(size_t)row * NBLK + blk] = e;
            parg[(size_t)row * NBLK + blk] = idx;
        }
    }
}

// ------- Kernel 3: parallel combine + fused last-block scalar epilogue ------
__global__ __launch_bounds__(256) void k_combine(
    const float* __restrict__ pmax, const float* __restrict__ psum,
    const int* __restrict__ parg, const float* __restrict__ tgt_logit,
    const int* __restrict__ ans_starts, const int* __restrict__ chain_targets,
    const int* __restrict__ chain_lens,
    float* __restrict__ logZ, int* __restrict__ pred,
    unsigned int* __restrict__ counter, float* __restrict__ out)
{
    int r = blockIdx.x;                 // row 0..63
    int tid = threadIdx.x;
    int wave = tid >> 6, lane = tid & 63;
    const float NEGINF = -__builtin_inff();

    const float* pm = pmax + (size_t)r * NBLK;
    const float* ps = psum + (size_t)r * NBLK;
    const int*   pa = parg + (size_t)r * NBLK;

    float M = NEGINF; int A_ = 0x7fffffff;
    for (int i = tid; i < NBLK; i += 256) {
        float m = pm[i];
        int a = pa[i];
        if (m > M || (m == M && a < A_)) { M = m; A_ = a; }
    }
#pragma unroll
    for (int off = 1; off < 64; off <<= 1) {
        float ov = __shfl_xor(M, off);
        int oa = __shfl_xor(A_, off);
        if (ov > M || (ov == M && oa < A_)) { M = ov; A_ = oa; }
    }
    __shared__ float sm[4]; __shared__ int sa[4]; __shared__ float ssum[4];
    __shared__ int lastflag;
    if (lane == 0) { sm[wave] = M; sa[wave] = A_; }
    __syncthreads();
    if (tid == 0) {
#pragma unroll
        for (int w = 1; w < 4; ++w)
            if (sm[w] > sm[0] || (sm[w] == sm[0] && sa[w] < sa[0])) { sm[0] = sm[w]; sa[0] = sa[w]; }
    }
    __syncthreads();
    float Mg = sm[0];

    float S = 0.f;
    for (int i = tid; i < NBLK; i += 256)
        S += ps[i] * __expf(pm[i] - Mg);
#pragma unroll
    for (int off = 1; off < 64; off <<= 1) S += __shfl_xor(S, off);
    if (lane == 0) ssum[wave] = S;
    __syncthreads();
    if (tid == 0) {
        float lz = Mg + logf(ssum[0] + ssum[1] + ssum[2] + ssum[3]);
        __hip_atomic_store(&logZ[r], lz, __ATOMIC_RELAXED, __HIP_MEMORY_SCOPE_AGENT);
        __hip_atomic_store(&pred[r], sa[0], __ATOMIC_RELAXED, __HIP_MEMORY_SCOPE_AGENT);
        __threadfence();                               // release
        unsigned int old = atomicAdd(counter, 1u);     // device-scope RMW
        lastflag = (old == 63u) ? 1 : 0;
    }
    __syncthreads();
    if (lastflag == 0) return;

    // ---- last block: scalar epilogue ----
    __threadfence();                                   // acquire
    __shared__ float lzs[64]; __shared__ int prs[64];
    if (tid < 64) {
        lzs[tid] = __hip_atomic_load(&logZ[tid], __ATOMIC_RELAXED, __HIP_MEMORY_SCOPE_AGENT);
        prs[tid] = __hip_atomic_load(&pred[tid], __ATOMIC_RELAXED, __HIP_MEMORY_SCOPE_AGENT);
    }
    __syncthreads();
    if (tid == 0) {
        float loop_loss[NLOOP], loop_acc[NLOOP], hasf[NLOOP];
        float n_has = 0.f, hms = 0.f, hcs = 0.f;
        for (int l = 0; l < NLOOP; ++l) {
            float cnt = 0.f, se = 0.f, sc = 0.f;
            for (int b = 0; b < BB; ++b) {
                int cl = chain_lens[b];
                int ti = l < cl - 1 ? l : cl - 1;
                int tgt = chain_targets[b * NLOOP + ti];
                int as = ans_starts[b];
                bool valid = (as >= 1) && (as < LLEN) && (tgt < VV);
                int idx = l * BB + b;
                float ce = lzs[idx] - tgt_logit[idx];
                float corr = (prs[idx] == tgt) ? 1.f : 0.f;
                if (valid) {
                    cnt += 1.f; se += ce; sc += corr;
                    if (tgt == HALT) { hms += 1.f; hcs += corr; }
                }
            }
            bool has = cnt > 0.f;
            hasf[l] = has ? 1.f : 0.f;
            n_has += hasf[l];
            float denom = cnt > 1.f ? cnt : 1.f;
            loop_loss[l] = has ? se / denom : 0.f;
            loop_acc[l]  = has ? sc / denom : 0.f;
        }
        float nn = n_has > 1.f ? n_has : 1.f;
        float avg_loss = 0.f, avg_acc = 0.f;
        for (int l = 0; l < NLOOP; ++l) {
            avg_loss += loop_loss[l] * hasf[l];
            avg_acc  += loop_acc[l]  * hasf[l];
        }
        avg_loss /= nn; avg_acc /= nn;
        int last_valid = NLOOP - 1;   // matches jnp.argmax on all-false reversed
        for (int l = NLOOP - 1; l >= 0; --l) if (hasf[l] > 0.f) { last_valid = l; break; }
        float ams = 0.f, aacc = 0.f;
        for (int l = 0; l < NLOOP; ++l) {
            float mask = (n_has > 1.f) ? (hasf[l] * ((l != last_valid) ? 1.f : 0.f)) : hasf[l];
            ams += mask; aacc += loop_acc[l] * mask;
        }
        float answer_acc = (ams > 0.f) ? (aacc / (ams > 1.f ? ams : 1.f)) : avg_acc;
        float halt_acc = (hms > 0.f) ? (hcs / (hms > 1.f ? hms : 1.f)) : 0.f;
        out[0] = avg_loss; out[1] = avg_acc; out[2] = answer_acc; out[3] = halt_acc;
    }
}

extern "C" void kernel_launch(void* const* d_in, const int* in_sizes, int n_in,
                              void* d_out, int out_size, void* d_ws, size_t ws_size,
                              hipStream_t stream) {
    const float* x   = (const float*)d_in[0];
    const float* res = (const float*)d_in[1];
    const float* nw  = (const float*)d_in[2];
    const float* W   = (const float*)d_in[3];
    const int* ans   = (const int*)d_in[4];
    const int* ct    = (const int*)d_in[5];
    const int* cl    = (const int*)d_in[6];
    float* out = (float*)d_out;

    char* ws = (char*)d_ws;
    unsigned short* hbf = (unsigned short*)ws;                       // 96 KiB
    float* tgtl = (float*)(ws + 98304);                              // 256 B
    size_t off = 98560;
    float* pmax = (float*)(ws + off);  off += (size_t)64 * NBLK * 4;
    float* psum = (float*)(ws + off);  off += (size_t)64 * NBLK * 4;
    int*   parg = (int*)  (ws + off);  off += (size_t)64 * NBLK * 4;
    float* logZ = (float*)(ws + off);  off += 256;
    int*   pred = (int*)  (ws + off);  off += 256;
    unsigned int* counter = (unsigned int*)(ws + off); off += 256;

    k_prep<<<64, 256, 0, stream>>>(x, res, nw, W, ans, ct, cl, hbf, tgtl, counter);
    k_logits<<<NBLK, 256, 0, stream>>>(W, hbf, pmax, psum, parg);
    k_combine<<<64, 256, 0, stream>>>(pmax, psum, parg, tgtl, ans, ct, cl,
                                      logZ, pred, counter, out);
}

// Round 5
// 57.815 us; speedup vs baseline: 1.7318x; 1.1111x over previous
//
#include <hip/hip_runtime.h>
#include <hip/hip_bf16.h>
#include <math.h>

#define NLOOP 8
#define BB 8
#define LLEN 2048
#define DD 768
#define VV 50288
#define HALT 50277
#define EPSF 1e-5f

#define BN 64
#define BKK 32
#define KSTEPS (DD / BKK)              // 24
#define NBLK ((VV + BN - 1) / BN)      // 786

typedef short bf16x8 __attribute__((ext_vector_type(8)));
typedef float f32x4 __attribute__((ext_vector_type(4)));

// lgkm-only barrier: ds ops drained, global loads stay in flight (counted vmcnt at use)
#define LGKM_BARRIER() asm volatile("s_waitcnt lgkmcnt(0)\n\ts_barrier" ::: "memory")

__device__ __forceinline__ unsigned short f32_to_bf16(float f) {
    unsigned u = __builtin_bit_cast(unsigned, f);
    unsigned r = (u + 0x7FFFu + ((u >> 16) & 1u)) >> 16;
    return (unsigned short)r;
}

// ---------------- Kernel 1: gather + RMSNorm + target logits ----------------
__global__ __launch_bounds__(256) void k_prep(
    const float* __restrict__ x, const float* __restrict__ res,
    const float* __restrict__ nw, const float* __restrict__ W,
    const int* __restrict__ ans_starts, const int* __restrict__ chain_targets,
    const int* __restrict__ chain_lens,
    unsigned short* __restrict__ hbf, float* __restrict__ tgt_logit,
    unsigned int* __restrict__ counter)
{
    if (blockIdx.x == 0 && threadIdx.x == 0) *counter = 0u;   // for k_combine

    int lb = blockIdx.x, l = lb >> 3, b = lb & 7;
    int tid = threadIdx.x, lane = tid & 63, wave = tid >> 6;
    int as = ans_starts[b];
    int pos = as - 1;
    pos = pos < 0 ? 0 : (pos > LLEN - 1 ? LLEN - 1 : pos);
    size_t base = ((size_t)lb * LLEN + (size_t)pos) * DD;

    float hv[3];
    float ss = 0.f;
#pragma unroll
    for (int i = 0; i < 3; ++i) {
        int d = tid + i * 256;
        float v = x[base + d] + res[base + d];
        hv[i] = v;
        ss += v * v;
    }
#pragma unroll
    for (int off = 32; off; off >>= 1) ss += __shfl_down(ss, off);
    __shared__ float red[4];
    __shared__ float bc;
    if (lane == 0) red[wave] = ss;
    __syncthreads();
    if (tid == 0) bc = red[0] + red[1] + red[2] + red[3];
    __syncthreads();
    float rs = rsqrtf(bc / (float)DD + EPSF);

    int cl = chain_lens[b];
    int tix = l < cl - 1 ? l : cl - 1;
    int tgt = chain_targets[b * NLOOP + tix];
    bool tok = (tgt >= 0) && (tgt < VV);

    float dp = 0.f;
#pragma unroll
    for (int i = 0; i < 3; ++i) {
        int d = tid + i * 256;
        float h = hv[i] * rs * nw[d];
        hbf[(size_t)lb * DD + d] = f32_to_bf16(h);
        if (tok) dp += h * W[(size_t)tgt * DD + d];
    }
#pragma unroll
    for (int off = 32; off; off >>= 1) dp += __shfl_down(dp, off);
    __syncthreads();
    if (lane == 0) red[wave] = dp;
    __syncthreads();
    if (tid == 0) tgt_logit[lb] = red[0] + red[1] + red[2] + red[3];
}

// ---------------- Kernel 2: A-in-registers MFMA logits ----------------------
// Wave w owns m-tile w (h rows 16w..16w+15) x all 64 block cols.
// A (h) preloaded to 24 bf16x8 regs once; B (W) staged global->reg->LDS,
// 4-deep register prefetch, double-buffered LDS, lgkm-only barrier per step
// (global loads stay in flight across barriers -> counted vmcnt).
// Partials written TRANSPOSED: pmax[row * NBLK + blk].
__global__ __launch_bounds__(256) void k_logits(
    const float* __restrict__ W, const unsigned short* __restrict__ hbf,
    float* __restrict__ pmax, float* __restrict__ psum, int* __restrict__ parg)
{
    __shared__ unsigned short Bs[2][64 * 56];   // 112B row stride (16B aligned)

    int blk = blockIdx.x;
    int v0 = blk * BN;
    int tid = threadIdx.x;
    int wave = tid >> 6, lane = tid & 63, q = lane >> 4, c = lane & 15;

    // ---- A preload: h row (16*wave + c), k = ks*32 + q*8 + j ----
    const unsigned short* Ap = hbf + (size_t)(16 * wave + c) * DD + q * 8;
    bf16x8 A[KSTEPS];
#pragma unroll
    for (int ks = 0; ks < KSTEPS; ++ks)
        A[ks] = *(const bf16x8*)(Ap + ks * BKK);

    // ---- B staging: thread loads rows r1, r1+32; 4 consecutive f32 at koff ----
    int r1 = tid >> 3, koff = (tid & 7) * 4;
    int vB0 = v0 + r1, vB1 = v0 + r1 + 32;
    const float* gB0 = W + (size_t)(vB0 < VV ? vB0 : 0) * DD + koff;  // clamp; cols masked later
    const float* gB1 = W + (size_t)(vB1 < VV ? vB1 : 0) * DD + koff;

    f32x4 acc[4];
#pragma unroll
    for (int n = 0; n < 4; ++n) acc[n] = (f32x4){0.f, 0.f, 0.f, 0.f};

    auto stage_write = [&](int bufi, const float4& ra, const float4& rb) {
        ushort4 w0, w1;
        w0.x = f32_to_bf16(ra.x); w0.y = f32_to_bf16(ra.y);
        w0.z = f32_to_bf16(ra.z); w0.w = f32_to_bf16(ra.w);
        w1.x = f32_to_bf16(rb.x); w1.y = f32_to_bf16(rb.y);
        w1.z = f32_to_bf16(rb.z); w1.w = f32_to_bf16(rb.w);
        *(ushort4*)&Bs[bufi][r1 * 56 + koff] = w0;
        *(ushort4*)&Bs[bufi][(r1 + 32) * 56 + koff] = w1;
    };
    auto mfma_step = [&](int bufi, int ks) {
        bf16x8 f0 = *(const bf16x8*)&Bs[bufi][(c +  0) * 56 + q * 8];
        bf16x8 f1 = *(const bf16x8*)&Bs[bufi][(c + 16) * 56 + q * 8];
        bf16x8 f2 = *(const bf16x8*)&Bs[bufi][(c + 32) * 56 + q * 8];
        bf16x8 f3 = *(const bf16x8*)&Bs[bufi][(c + 48) * 56 + q * 8];
        acc[0] = __builtin_amdgcn_mfma_f32_16x16x32_bf16(A[ks], f0, acc[0], 0, 0, 0);
        acc[1] = __builtin_amdgcn_mfma_f32_16x16x32_bf16(A[ks], f1, acc[1], 0, 0, 0);
        acc[2] = __builtin_amdgcn_mfma_f32_16x16x32_bf16(A[ks], f2, acc[2], 0, 0, 0);
        acc[3] = __builtin_amdgcn_mfma_f32_16x16x32_bf16(A[ks], f3, acc[3], 0, 0, 0);
    };

    // 4-deep register pipeline (named sets, static indexing via full unroll)
    float4 pa[4], pb[4];
#pragma unroll
    for (int i = 0; i < 4; ++i) {
        pa[i] = *(const float4*)(gB0 + i * BKK);
        pb[i] = *(const float4*)(gB1 + i * BKK);
    }

#pragma unroll
    for (int ks = 0; ks < KSTEPS; ++ks) {       // fully unrolled: slots static
        const int slot = ks & 3;
        const int bufi = ks & 1;
        stage_write(bufi, pa[slot], pb[slot]);
        LGKM_BARRIER();
        if (ks + 4 < KSTEPS) {
            pa[slot] = *(const float4*)(gB0 + (ks + 4) * BKK);
            pb[slot] = *(const float4*)(gB1 + (ks + 4) * BKK);
        }
        mfma_step(bufi, ks);
    }

    // ---- wave-internal per-row max / argmax / sumexp over 64 block cols ----
    const float NEGINF = -__builtin_inff();
#pragma unroll
    for (int r = 0; r < 4; ++r) {
        float val = NEGINF; int idx = 0x7fffffff;
#pragma unroll
        for (int n = 0; n < 4; ++n) {
            int colg = v0 + 16 * n + c;
            float v = (colg < VV) ? acc[n][r] : NEGINF;
            if (v > val || (v == val && colg < idx)) { val = v; idx = colg; }
        }
#pragma unroll
        for (int off = 1; off < 16; off <<= 1) {
            float ov = __shfl_xor(val, off);
            int oi = __shfl_xor(idx, off);
            if (ov > val || (ov == val && oi < idx)) { val = ov; idx = oi; }
        }
        float M = val;          // all 16 lanes of the q-group hold the row max
        float e = 0.f;
#pragma unroll
        for (int n = 0; n < 4; ++n) {
            int colg = v0 + 16 * n + c;
            e += (colg < VV) ? __expf(acc[n][r] - M) : 0.f;
        }
#pragma unroll
        for (int off = 1; off < 16; off <<= 1) e += __shfl_xor(e, off);
        if (c == 0) {
            int row = 16 * wave + 4 * q + r;
            pmax[(size_t)row * NBLK + blk] = M;
            psum[(size_t)row * NBLK + blk] = e;
            parg[(size_t)row * NBLK + blk] = idx;
        }
    }
}

// ------- Kernel 3: parallel combine + fused last-block scalar epilogue ------
__global__ __launch_bounds__(256) void k_combine(
    const float* __restrict__ pmax, const float* __restrict__ psum,
    const int* __restrict__ parg, const float* __restrict__ tgt_logit,
    const int* __restrict__ ans_starts, const int* __restrict__ chain_targets,
    const int* __restrict__ chain_lens,
    float* __restrict__ logZ, int* __restrict__ pred,
    unsigned int* __restrict__ counter, float* __restrict__ out)
{
    int r = blockIdx.x;                 // row 0..63
    int tid = threadIdx.x;
    int wave = tid >> 6, lane = tid & 63;
    const float NEGINF = -__builtin_inff();

    const float* pm = pmax + (size_t)r * NBLK;
    const float* ps = psum + (size_t)r * NBLK;
    const int*   pa = parg + (size_t)r * NBLK;

    float M = NEGINF; int A_ = 0x7fffffff;
    for (int i = tid; i < NBLK; i += 256) {
        float m = pm[i];
        int a = pa[i];
        if (m > M || (m == M && a < A_)) { M = m; A_ = a; }
    }
#pragma unroll
    for (int off = 1; off < 64; off <<= 1) {
        float ov = __shfl_xor(M, off);
        int oa = __shfl_xor(A_, off);
        if (ov > M || (ov == M && oa < A_)) { M = ov; A_ = oa; }
    }
    __shared__ float sm[4]; __shared__ int sa[4]; __shared__ float ssum[4];
    __shared__ int lastflag;
    if (lane == 0) { sm[wave] = M; sa[wave] = A_; }
    __syncthreads();
    if (tid == 0) {
#pragma unroll
        for (int w = 1; w < 4; ++w)
            if (sm[w] > sm[0] || (sm[w] == sm[0] && sa[w] < sa[0])) { sm[0] = sm[w]; sa[0] = sa[w]; }
    }
    __syncthreads();
    float Mg = sm[0];

    float S = 0.f;
    for (int i = tid; i < NBLK; i += 256)
        S += ps[i] * __expf(pm[i] - Mg);
#pragma unroll
    for (int off = 1; off < 64; off <<= 1) S += __shfl_xor(S, off);
    if (lane == 0) ssum[wave] = S;
    __syncthreads();
    if (tid == 0) {
        float lz = Mg + logf(ssum[0] + ssum[1] + ssum[2] + ssum[3]);
        __hip_atomic_store(&logZ[r], lz, __ATOMIC_RELAXED, __HIP_MEMORY_SCOPE_AGENT);
        __hip_atomic_store(&pred[r], sa[0], __ATOMIC_RELAXED, __HIP_MEMORY_SCOPE_AGENT);
        __threadfence();                               // release
        unsigned int old = atomicAdd(counter, 1u);     // device-scope RMW
        lastflag = (old == 63u) ? 1 : 0;
    }
    __syncthreads();
    if (lastflag == 0) return;

    // ---- last block: scalar epilogue ----
    __threadfence();                                   // acquire
    __shared__ float lzs[64]; __shared__ int prs[64];
    if (tid < 64) {
        lzs[tid] = __hip_atomic_load(&logZ[tid], __ATOMIC_RELAXED, __HIP_MEMORY_SCOPE_AGENT);
        prs[tid] = __hip_atomic_load(&pred[tid], __ATOMIC_RELAXED, __HIP_MEMORY_SCOPE_AGENT);
    }
    __syncthreads();
    if (tid == 0) {
        float loop_loss[NLOOP], loop_acc[NLOOP], hasf[NLOOP];
        float n_has = 0.f, hms = 0.f, hcs = 0.f;
        for (int l = 0; l < NLOOP; ++l) {
            float cnt = 0.f, se = 0.f, sc = 0.f;
            for (int b = 0; b < BB; ++b) {
                int cl = chain_lens[b];
                int ti = l < cl - 1 ? l : cl - 1;
                int tgt = chain_targets[b * NLOOP + ti];
                int as = ans_starts[b];
                bool valid = (as >= 1) && (as < LLEN) && (tgt < VV);
                int idx = l * BB + b;
                float ce = lzs[idx] - tgt_logit[idx];
                float corr = (prs[idx] == tgt) ? 1.f : 0.f;
                if (valid) {
                    cnt += 1.f; se += ce; sc += corr;
                    if (tgt == HALT) { hms += 1.f; hcs += corr; }
                }
            }
            bool has = cnt > 0.f;
            hasf[l] = has ? 1.f : 0.f;
            n_has += hasf[l];
            float denom = cnt > 1.f ? cnt : 1.f;
            loop_loss[l] = has ? se / denom : 0.f;
            loop_acc[l]  = has ? sc / denom : 0.f;
        }
        float nn = n_has > 1.f ? n_has : 1.f;
        float avg_loss = 0.f, avg_acc = 0.f;
        for (int l = 0; l < NLOOP; ++l) {
            avg_loss += loop_loss[l] * hasf[l];
            avg_acc  += loop_acc[l]  * hasf[l];
        }
        avg_loss /= nn; avg_acc /= nn;
        int last_valid = NLOOP - 1;   // matches jnp.argmax on all-false reversed
        for (int l = NLOOP - 1; l >= 0; --l) if (hasf[l] > 0.f) { last_valid = l; break; }
        float ams = 0.f, aacc = 0.f;
        for (int l = 0; l < NLOOP; ++l) {
            float mask = (n_has > 1.f) ? (hasf[l] * ((l != last_valid) ? 1.f : 0.f)) : hasf[l];
            ams += mask; aacc += loop_acc[l] * mask;
        }
        float answer_acc = (ams > 0.f) ? (aacc / (ams > 1.f ? ams : 1.f)) : avg_acc;
        float halt_acc = (hms > 0.f) ? (hcs / (hms > 1.f ? hms : 1.f)) : 0.f;
        out[0] = avg_loss; out[1] = avg_acc; out[2] = answer_acc; out[3] = halt_acc;
    }
}

extern "C" void kernel_launch(void* const* d_in, const int* in_sizes, int n_in,
                              void* d_out, int out_size, void* d_ws, size_t ws_size,
                              hipStream_t stream) {
    const float* x   = (const float*)d_in[0];
    const float* res = (const float*)d_in[1];
    const float* nw  = (const float*)d_in[2];
    const float* W   = (const float*)d_in[3];
    const int* ans   = (const int*)d_in[4];
    const int* ct    = (const int*)d_in[5];
    const int* cl    = (const int*)d_in[6];
    float* out = (float*)d_out;

    char* ws = (char*)d_ws;
    unsigned short* hbf = (unsigned short*)ws;                       // 96 KiB
    float* tgtl = (float*)(ws + 98304);                              // 256 B
    size_t off = 98560;
    float* pmax = (float*)(ws + off);  off += (size_t)64 * NBLK * 4;
    float* psum = (float*)(ws + off);  off += (size_t)64 * NBLK * 4;
    int*   parg = (int*)  (ws + off);  off += (size_t)64 * NBLK * 4;
    float* logZ = (float*)(ws + off);  off += 256;
    int*   pred = (int*)  (ws + off);  off += 256;
    unsigned int* counter = (unsigned int*)(ws + off); off += 256;

    k_prep<<<64, 256, 0, stream>>>(x, res, nw, W, ans, ct, cl, hbf, tgtl, counter);
    k_logits<<<NBLK, 256, 0, stream>>>(W, hbf, pmax, psum, parg);
    k_combine<<<64, 256, 0, stream>>>(pmax, psum, parg, tgtl, ans, ct, cl,
                                      logZ, pred, counter, out);
}